// Round 1
// baseline (555.522 us; speedup 1.0000x reference)
//
#include <hip/hip_runtime.h>

typedef unsigned short u16;
typedef __attribute__((ext_vector_type(8))) short bf16x8;
typedef __attribute__((ext_vector_type(4))) float f32x4;

// B=4, C=Cin=256, H=W=128. NHWC bf16 activations for implicit-GEMM MFMA.

__device__ __forceinline__ u16 f2bf(float f) {
  unsigned u = __float_as_uint(f);
  unsigned r = u + 0x7fffu + ((u >> 16) & 1u);
  return (u16)(r >> 16);
}

// ---------------- BN prep: s = g*rsqrt(v+eps), t = b - m*s ----------------
__global__ void bn_prep_kernel(const float* __restrict__ g, const float* __restrict__ b,
                               const float* __restrict__ m, const float* __restrict__ v,
                               float* __restrict__ st) {
  int c = threadIdx.x;
  float s = g[c] * rsqrtf(v[c] + 1e-5f);
  st[c] = s;
  st[256 + c] = b[c] - m[c] * s;
}

// fold c1 BN into merge: t_p += t_c1 ; ratio = s_c1/s_p stored in c1's s-slot
__global__ void bn_fix_kernel(float* __restrict__ st) {
  int c = threadIdx.x;
  st[2 * 512 + 256 + c] += st[3 * 512 + 256 + c];
  st[3 * 512 + c] = st[3 * 512 + c] / st[2 * 512 + c];
}

// ---------------- weight prep: dst[s][co][ci] = w[co][ci][s] * scale?[co] ----------------
__global__ void wprep_kernel(const float* __restrict__ w, u16* __restrict__ dst,
                             int S, const float* __restrict__ scale, int total) {
  int idx = blockIdx.x * 256 + threadIdx.x;
  if (idx >= total) return;
  int s = idx >> 16;           // 65536 = 256co*256ci per shift
  int rem = idx & 65535;
  int co = rem >> 8, ci = rem & 255;
  float f = w[(co * 256 + ci) * S + s];
  if (scale) f *= scale[co];
  dst[idx] = f2bf(f);
}

// ---------------- NCHW fp32 -> NHWC bf16 (LDS tiled transpose) ----------------
__global__ __launch_bounds__(256) void nchw_to_nhwc_kernel(const float* __restrict__ x,
                                                           u16* __restrict__ xb) {
  __shared__ __align__(16) u16 tl[128 * 130];
  int bh = blockIdx.x; int b = bh >> 7, h = bh & 127;
  int t = threadIdx.x;
  for (int half = 0; half < 2; ++half) {
    __syncthreads();
    // phase 1: read [128ci x 128w] coalesced along w, write LDS [w][ci_local]
    for (int i = 0; i < 64; ++i) {
      int cil = i * 2 + (t >> 7);
      int ci = half * 128 + cil;
      int w = t & 127;
      float v = x[(size_t)((b * 256 + ci) * 128 + h) * 128 + w];
      tl[w * 130 + cil] = f2bf(v);
    }
    __syncthreads();
    // phase 2: write NHWC, coalesced along ci
    for (int i = 0; i < 32; ++i) {
      int w = i * 4 + (t >> 6);
      int c2 = (t & 63) * 2;
      unsigned v = *(const unsigned*)&tl[w * 130 + c2];
      *(unsigned*)&xb[(size_t)((b * 128 + h) * 128 + w) * 256 + half * 128 + c2] = v;
    }
  }
}

// ---------------- shared conv implicit-GEMM mainloop ----------------
// out tile [128co x 128n] per (b,h); n == w. BK=32, 4 waves, 16x16x32 bf16 MFMA.
// LDS tiles [row][32k] bf16, pitch 64B, chunk-XOR swizzle (chunk ^= (row>>1)&3).
__device__ __forceinline__ void conv_mainloop(const u16* __restrict__ in,
                                              const u16* __restrict__ wp,
                                              int b, int h, int co_base, int S,
                                              char* lds, f32x4 (&acc)[4][4]) {
  const int t = threadIdx.x;
  const int lane = t & 63;
  const int wv = t >> 6;
  const int co_half = wv >> 1, n_half = wv & 1;
  const int rowA = t >> 2, chunk = t & 3;

  for (int s = 0; s < S; ++s) {
    const int dh = (S == 9) ? (s / 3 - 1) : 0;
    const int dw = (S == 9) ? (s % 3 - 1) : 0;
    const int hp = h + dh;
    const bool hok = ((unsigned)hp) < 128u;
    const u16* wrow = wp + (size_t)s * 65536 + (size_t)co_base * 256;
    const int w0 = rowA + dw;
    const int w1 = rowA + 64 + dw;
    const bool ok0 = hok && ((unsigned)w0) < 128u;
    const bool ok1 = hok && ((unsigned)w1) < 128u;
    for (int kc = 0; kc < 8; ++kc) {
      const int ci0 = kc * 32 + chunk * 8;
      __syncthreads();
      int4 va0 = *(const int4*)(wrow + (size_t)rowA * 256 + ci0);
      int4 va1 = *(const int4*)(wrow + (size_t)(rowA + 64) * 256 + ci0);
      int4 vb0 = {0, 0, 0, 0}, vb1 = {0, 0, 0, 0};
      if (ok0) vb0 = *(const int4*)(in + (size_t)((b * 128 + hp) * 128 + w0) * 256 + ci0);
      if (ok1) vb1 = *(const int4*)(in + (size_t)((b * 128 + hp) * 128 + w1) * 256 + ci0);
      {
        int sw = (chunk ^ ((rowA >> 1) & 3)) << 4;  // (rowA+64) has same (row>>1)&3
        *(int4*)(lds + rowA * 64 + sw) = va0;
        *(int4*)(lds + (rowA + 64) * 64 + sw) = va1;
        *(int4*)(lds + 8192 + rowA * 64 + sw) = vb0;
        *(int4*)(lds + 8192 + (rowA + 64) * 64 + sw) = vb1;
      }
      __syncthreads();
      bf16x8 af[4], bfr[4];
#pragma unroll
      for (int f = 0; f < 4; ++f) {
        int ra = co_half * 64 + f * 16 + (lane & 15);
        af[f] = *(const bf16x8*)(lds + ra * 64 + (((lane >> 4) ^ ((ra >> 1) & 3)) << 4));
        int rb = n_half * 64 + f * 16 + (lane & 15);
        bfr[f] = *(const bf16x8*)(lds + 8192 + rb * 64 + (((lane >> 4) ^ ((rb >> 1) & 3)) << 4));
      }
#pragma unroll
      for (int fm = 0; fm < 4; ++fm)
#pragma unroll
        for (int fn = 0; fn < 4; ++fn)
          acc[fm][fn] = __builtin_amdgcn_mfma_f32_16x16x32_bf16(af[fm], bfr[fn], acc[fm][fn], 0, 0, 0);
    }
  }
}

__device__ __forceinline__ void zero_acc(f32x4 (&acc)[4][4]) {
  f32x4 z = {0.f, 0.f, 0.f, 0.f};
#pragma unroll
  for (int i = 0; i < 4; ++i)
#pragma unroll
    for (int j = 0; j < 4; ++j) acc[i][j] = z;
}

// epilogue: BN+ReLU, store NHWC bf16 (4 consecutive co per lane -> 8B store)
__device__ __forceinline__ void store_nhwc_relu(f32x4 (&acc)[4][4], const float* __restrict__ st,
                                                int co_base, int b, int h, u16* __restrict__ out) {
  const int t = threadIdx.x, lane = t & 63, wv = t >> 6;
  const int co_half = wv >> 1, n_half = wv & 1;
  const float* sp = st;
  const float* tp = st + 256;
#pragma unroll
  for (int fm = 0; fm < 4; ++fm) {
    int co_l = co_base + co_half * 64 + fm * 16 + ((lane >> 4) << 2);
    float ss[4], tt[4];
#pragma unroll
    for (int r = 0; r < 4; ++r) { ss[r] = sp[co_l + r]; tt[r] = tp[co_l + r]; }
#pragma unroll
    for (int fn = 0; fn < 4; ++fn) {
      int n = n_half * 64 + fn * 16 + (lane & 15);
      short4 o;
      o.x = (short)f2bf(fmaxf(acc[fm][fn][0] * ss[0] + tt[0], 0.f));
      o.y = (short)f2bf(fmaxf(acc[fm][fn][1] * ss[1] + tt[1], 0.f));
      o.z = (short)f2bf(fmaxf(acc[fm][fn][2] * ss[2] + tt[2], 0.f));
      o.w = (short)f2bf(fmaxf(acc[fm][fn][3] * ss[3] + tt[3], 0.f));
      *(short4*)(out + (size_t)((b * 128 + h) * 128 + n) * 256 + co_l) = o;
    }
  }
}

// ---------------- up conv: BN+ReLU then fused row-max (over full W tile) ----------------
__global__ __launch_bounds__(256) void conv_up_kernel(const u16* __restrict__ xb,
                                                      const u16* __restrict__ wp,
                                                      const float* __restrict__ st,
                                                      float* __restrict__ rmax) {
  __shared__ __align__(16) char lds[16384];
  int bh = blockIdx.x; int b = bh >> 7, h = bh & 127;
  int co_base = blockIdx.y * 128;
  f32x4 acc[4][4];
  zero_acc(acc);
  conv_mainloop(xb, wp, b, h, co_base, 9, lds, acc);

  const int t = threadIdx.x, lane = t & 63, wv = t >> 6;
  const int co_half = wv >> 1, n_half = wv & 1;
  __syncthreads();
  float* rlds = (float*)lds;
  const float* sp = st;
  const float* tp = st + 256;
#pragma unroll
  for (int fm = 0; fm < 4; ++fm) {
    int co_l = co_half * 64 + fm * 16 + ((lane >> 4) << 2);
#pragma unroll
    for (int r = 0; r < 4; ++r) {
      float ss = sp[co_base + co_l + r], tt = tp[co_base + co_l + r];
      float v = 0.f;  // relu'd values are >= 0
#pragma unroll
      for (int fn = 0; fn < 4; ++fn) v = fmaxf(v, acc[fm][fn][r] * ss + tt);
      v = fmaxf(v, __shfl_xor(v, 1));
      v = fmaxf(v, __shfl_xor(v, 2));
      v = fmaxf(v, __shfl_xor(v, 4));
      v = fmaxf(v, __shfl_xor(v, 8));
      if ((lane & 15) == 0) rlds[n_half * 128 + co_l + r] = v;
    }
  }
  __syncthreads();
  if (t < 128) {
    float v = fmaxf(rlds[t], rlds[128 + t]);
    rmax[(size_t)(b * 128 + h) * 256 + co_base + t] = v;
  }
}

// ---------------- down conv: BN+ReLU, write NHWC bf16 ----------------
__global__ __launch_bounds__(256) void conv_down_kernel(const u16* __restrict__ xb,
                                                        const u16* __restrict__ wp,
                                                        const float* __restrict__ st,
                                                        u16* __restrict__ out) {
  __shared__ __align__(16) char lds[16384];
  int bh = blockIdx.x; int b = bh >> 7, h = bh & 127;
  int co_base = blockIdx.y * 128;
  f32x4 acc[4][4];
  zero_acc(acc);
  conv_mainloop(xb, wp, b, h, co_base, 9, lds, acc);
  store_nhwc_relu(acc, st, co_base, b, h, out);
}

// ---------------- col max over H ----------------
__global__ __launch_bounds__(256) void colmax_kernel(const u16* __restrict__ down,
                                                     float* __restrict__ cmax) {
  int bw = blockIdx.x; int b = bw >> 7, w = bw & 127;
  int c = threadIdx.x;
  float m = 0.f;
  for (int h = 0; h < 128; ++h) {
    unsigned u = ((unsigned)down[(size_t)((b * 128 + h) * 128 + w) * 256 + c]) << 16;
    m = fmaxf(m, __uint_as_float(u));
  }
  cmax[(size_t)(b * 128 + w) * 256 + c] = m;
}

// ---------------- pooled[b,h,w,c] = rmax[b,h,c] + cmax[b,w,c] (bf16) ----------------
__global__ __launch_bounds__(256) void pooled_kernel(const float* __restrict__ rmax,
                                                     const float* __restrict__ cmax,
                                                     u16* __restrict__ pooled) {
  int bh = blockIdx.x; int b = bh >> 7, h = bh & 127;
  int c = threadIdx.x;
  float rm = rmax[(size_t)(b * 128 + h) * 256 + c];
  for (int w = 0; w < 128; ++w) {
    float v = rm + cmax[(size_t)(b * 128 + w) * 256 + c];
    pooled[(size_t)((b * 128 + h) * 128 + w) * 256 + c] = f2bf(v);
  }
}

// ---------------- merge conv (pooled, 9 shifts) + fused 1x1 c1 (xb), BN, ReLU ----------------
__global__ __launch_bounds__(256) void conv_merge_kernel(const u16* __restrict__ pooled,
                                                         const u16* __restrict__ xb,
                                                         const u16* __restrict__ wp_p,
                                                         const u16* __restrict__ wp_c1,
                                                         const float* __restrict__ st,
                                                         u16* __restrict__ out) {
  __shared__ __align__(16) char lds[16384];
  int bh = blockIdx.x; int b = bh >> 7, h = bh & 127;
  int co_base = blockIdx.y * 128;
  f32x4 acc[4][4];
  zero_acc(acc);
  conv_mainloop(pooled, wp_p, b, h, co_base, 9, lds, acc);
  conv_mainloop(xb, wp_c1, b, h, co_base, 1, lds, acc);  // c1 weights pre-scaled by s_c1/s_p
  store_nhwc_relu(acc, st, co_base, b, h, out);
}

// ---------------- final conv c2: BN+ReLU, write NCHW fp32 via LDS transpose ----------------
__global__ __launch_bounds__(256) void conv_c2_kernel(const u16* __restrict__ relu1,
                                                      const u16* __restrict__ wp,
                                                      const float* __restrict__ st,
                                                      float* __restrict__ out) {
  __shared__ __align__(16) char lds[16384];
  int bh = blockIdx.x; int b = bh >> 7, h = bh & 127;
  int co_base = blockIdx.y * 128;
  f32x4 acc[4][4];
  zero_acc(acc);
  conv_mainloop(relu1, wp, b, h, co_base, 9, lds, acc);

  const int t = threadIdx.x, lane = t & 63, wv = t >> 6;
  const int co_half = wv >> 1, n_half = wv & 1;
  float* tl = (float*)lds;  // [16][132] fp32 per co-group
  const float* sp = st;
  const float* tp = st + 256;
  for (int g = 0; g < 8; ++g) {
    __syncthreads();
    if (co_half == (g >> 2)) {
      int fm = g & 3;
      int cr0 = (lane >> 4) << 2;
      int co_l = co_base + co_half * 64 + fm * 16 + cr0;
#pragma unroll
      for (int r = 0; r < 4; ++r) {
        float ss = sp[co_l + r], tt = tp[co_l + r];
#pragma unroll
        for (int fn = 0; fn < 4; ++fn) {
          int n = n_half * 64 + fn * 16 + (lane & 15);
          tl[(cr0 + r) * 132 + n] = fmaxf(acc[fm][fn][r] * ss + tt, 0.f);
        }
      }
    }
    __syncthreads();
    {
      int row = t >> 4, ch = t & 15;
      float4 p0 = *(float4*)&tl[row * 132 + ch * 8];
      float4 p1 = *(float4*)&tl[row * 132 + ch * 8 + 4];
      int co = co_base + g * 16 + row;
      float* dst = out + (size_t)((b * 256 + co) * 128 + h) * 128 + ch * 8;
      *(float4*)dst = p0;
      *(float4*)(dst + 4) = p1;
    }
  }
}

extern "C" void kernel_launch(void* const* d_in, const int* in_sizes, int n_in,
                              void* d_out, int out_size, void* d_ws, size_t ws_size,
                              hipStream_t stream) {
  (void)in_sizes; (void)n_in; (void)out_size; (void)ws_size;
  const float* x    = (const float*)d_in[0];
  const float* w_up = (const float*)d_in[1];
  const float* w_dn = (const float*)d_in[6];
  const float* w_p  = (const float*)d_in[11];
  const float* w_c1 = (const float*)d_in[16];
  const float* w_c2 = (const float*)d_in[21];

  // ws layout (bytes) — total ~106.6 MB
  char* ws = (char*)d_ws;
  u16* xb     = (u16*)(ws);                       // 33,554,432  NHWC bf16 x
  u16* dp     = (u16*)(ws + 33554432ull);         // 33,554,432  down, then pooled (alias)
  u16* relu1  = (u16*)(ws + 67108864ull);         // 33,554,432
  u16* wp_up  = (u16*)(ws + 100663296ull);        // 1,179,648
  u16* wp_dn  = (u16*)(ws + 101842944ull);        // 1,179,648
  u16* wp_p   = (u16*)(ws + 103022592ull);        // 1,179,648
  u16* wp_c2  = (u16*)(ws + 104202240ull);        // 1,179,648
  u16* wp_c1  = (u16*)(ws + 105381888ull);        // 131,072
  float* st   = (float*)(ws + 105512960ull);      // 10,240 = 5 convs x [s(256), t(256)]
  float* rmax = (float*)(ws + 105523200ull);      // 524,288  [b][h][c]
  float* cmax = (float*)(ws + 106047488ull);      // 524,288  [b][w][c]

  bn_prep_kernel<<<1, 256, 0, stream>>>((const float*)d_in[2], (const float*)d_in[3],
                                        (const float*)d_in[4], (const float*)d_in[5], st);
  bn_prep_kernel<<<1, 256, 0, stream>>>((const float*)d_in[7], (const float*)d_in[8],
                                        (const float*)d_in[9], (const float*)d_in[10], st + 512);
  bn_prep_kernel<<<1, 256, 0, stream>>>((const float*)d_in[12], (const float*)d_in[13],
                                        (const float*)d_in[14], (const float*)d_in[15], st + 1024);
  bn_prep_kernel<<<1, 256, 0, stream>>>((const float*)d_in[17], (const float*)d_in[18],
                                        (const float*)d_in[19], (const float*)d_in[20], st + 1536);
  bn_prep_kernel<<<1, 256, 0, stream>>>((const float*)d_in[22], (const float*)d_in[23],
                                        (const float*)d_in[24], (const float*)d_in[25], st + 2048);
  bn_fix_kernel<<<1, 256, 0, stream>>>(st);

  wprep_kernel<<<2304, 256, 0, stream>>>(w_up, wp_up, 9, nullptr, 589824);
  wprep_kernel<<<2304, 256, 0, stream>>>(w_dn, wp_dn, 9, nullptr, 589824);
  wprep_kernel<<<2304, 256, 0, stream>>>(w_p, wp_p, 9, nullptr, 589824);
  wprep_kernel<<<2304, 256, 0, stream>>>(w_c2, wp_c2, 9, nullptr, 589824);
  wprep_kernel<<<256, 256, 0, stream>>>(w_c1, wp_c1, 1, st + 1536, 65536);  // scaled by s_c1/s_p

  nchw_to_nhwc_kernel<<<512, 256, 0, stream>>>(x, xb);

  conv_up_kernel<<<dim3(512, 2), 256, 0, stream>>>(xb, wp_up, st, rmax);
  conv_down_kernel<<<dim3(512, 2), 256, 0, stream>>>(xb, wp_dn, st + 512, dp);
  colmax_kernel<<<512, 256, 0, stream>>>(dp, cmax);
  pooled_kernel<<<512, 256, 0, stream>>>(rmax, cmax, dp);  // overwrite down with pooled
  conv_merge_kernel<<<dim3(512, 2), 256, 0, stream>>>(dp, xb, wp_p, wp_c1, st + 1024, relu1);
  conv_c2_kernel<<<dim3(512, 2), 256, 0, stream>>>(relu1, wp_c2, st + 2048, (float*)d_out);
}

// Round 2
// 429.075 us; speedup vs baseline: 1.2947x; 1.2947x over previous
//
#include <hip/hip_runtime.h>

typedef unsigned short u16;
typedef __attribute__((ext_vector_type(8))) short bf16x8;
typedef __attribute__((ext_vector_type(4))) float f32x4;

// B=4, C=Cin=256, H=W=128.
// Activations live in a "staging-ready" global layout:
//   [b][h][half(ci>>7)][w][256B], with each 256B half-row internally XOR-swizzled
//   by key ((w+1)&7)<<4 so that a LINEAR global_load_lds lands it bank-conflict-free
//   for ds_read_b128 MFMA fragments (LDS row = wp = w+1).
// plane(b,h) = 65536 B, batch = 8,388,608 B, tensor = 32 MB.

__device__ __forceinline__ u16 f2bf(float f) {
  unsigned u = __float_as_uint(f);
  unsigned r = u + 0x7fffu + ((u >> 16) & 1u);
  return (u16)(r >> 16);
}

__device__ __forceinline__ void gll16(const char* g, char* l) {
  __builtin_amdgcn_global_load_lds((const __attribute__((address_space(1))) void*)g,
                                   (__attribute__((address_space(3))) void*)l, 16, 0, 0);
}

// ---------------- BN prep: s = g*rsqrt(v+eps), t = b - m*s ----------------
__global__ void bn_prep_kernel(const float* __restrict__ g, const float* __restrict__ b,
                               const float* __restrict__ m, const float* __restrict__ v,
                               float* __restrict__ st) {
  int c = threadIdx.x;
  float s = g[c] * rsqrtf(v[c] + 1e-5f);
  st[c] = s;
  st[256 + c] = b[c] - m[c] * s;
}

// fold c1 BN into merge: t_p += t_c1 ; ratio = s_c1/s_p stored in c1's s-slot
__global__ void bn_fix_kernel(float* __restrict__ st) {
  int c = threadIdx.x;
  st[2 * 512 + 256 + c] += st[3 * 512 + 256 + c];
  st[3 * 512 + c] = st[3 * 512 + c] / st[2 * 512 + c];
}

// ---------------- weight prep: per-step 16KB blocks in exact LDS image ----------------
// A-LDS block: [256 co][64B row], byte-in-row = (slot^((co>>1)&3))*16 + e*2,
//   element ci = half*128 + kc*32 + q*8 + e  (q = stored-slot decoded back)
// block index blk = ((half*3 + d)*3 + dwi)*4 + kc, s = d*3 + dwi.
__global__ void wprep3_kernel(const float* __restrict__ w, u16* __restrict__ dst) {
  int idx = blockIdx.x * 256 + threadIdx.x;        // 589,824 u16
  int blk = idx >> 13, iu = idx & 8191;
  int co = iu >> 5, w32 = iu & 31, slot = w32 >> 3, e = w32 & 7;
  int q = slot ^ ((co >> 1) & 3);
  int kc = blk & 3, t = blk >> 2;
  int dwi = t % 3, t2 = t / 3, d = t2 % 3, half = t2 / 3;
  int s = d * 3 + dwi;
  int ci = half * 128 + kc * 32 + q * 8 + e;
  dst[idx] = f2bf(w[(co * 256 + ci) * 9 + s]);
}

__global__ void wprep1_kernel(const float* __restrict__ w, u16* __restrict__ dst,
                              const float* __restrict__ ratio) {
  int idx = blockIdx.x * 256 + threadIdx.x;        // 65,536 u16, blk = half*4+kc
  int blk = idx >> 13, iu = idx & 8191;
  int co = iu >> 5, w32 = iu & 31, slot = w32 >> 3, e = w32 & 7;
  int q = slot ^ ((co >> 1) & 3);
  int kc = blk & 3, half = blk >> 2;
  int ci = half * 128 + kc * 32 + q * 8 + e;
  dst[idx] = f2bf(w[co * 256 + ci] * ratio[co]);
}

// ---------------- NCHW fp32 -> staging layout bf16 ----------------
__global__ __launch_bounds__(256) void nchw_to_nhwc_kernel(const float* __restrict__ x,
                                                           char* __restrict__ xb) {
  __shared__ __align__(16) u16 tl[128 * 130];
  int bh = blockIdx.x; int b = bh >> 7, h = bh & 127;
  int t = threadIdx.x;
  for (int half = 0; half < 2; ++half) {
    __syncthreads();
    for (int i = 0; i < 64; ++i) {
      int cil = i * 2 + (t >> 7);
      int ci = half * 128 + cil;
      int w = t & 127;
      tl[w * 130 + cil] = f2bf(x[(size_t)((b * 256 + ci) * 128 + h) * 128 + w]);
    }
    __syncthreads();
    char* plane = xb + (size_t)(b * 128 + h) * 65536 + half * 32768;
    for (int i = 0; i < 32; ++i) {
      int w = i * 4 + (t >> 6);
      int c2 = (t & 63) * 2;   // u16 index within half
      unsigned v = *(const unsigned*)&tl[w * 130 + c2];
      *(unsigned*)(plane + w * 256 + ((c2 * 2) ^ (((w + 1) & 7) << 4))) = v;
    }
  }
}

// ---------------- shared 8-wave conv pipeline ----------------
// Block: 512 thr (8 waves), output [256 co][128 w] at fixed (b,h).
// LDS: B rows wp 0..129 (33,280B) + A double-buffer 2x16,384B = 66,048B.
// 2-phase: stage A[i+1] -> ds_read+MFMA on A[i] -> barrier (drains vmcnt).
__device__ __forceinline__ void conv_pipeline(const char* inB1, const char* inB2,
                                              const char* wA1, const char* wA2,
                                              int h, int nsteps, char* lds,
                                              f32x4 (&acc)[4][4]) {
  const int t = threadIdx.x;
  const int wv = t >> 6, lane = t & 63;
  const int lane15 = lane & 15, q = lane >> 4;
  const int coq = wv >> 1, wh = wv & 1;
  char* ldsB = lds;
  char* ldsA0 = lds + 33280;

  int aOff[4];
#pragma unroll
  for (int f = 0; f < 4; ++f) {
    int ra = coq * 64 + f * 16 + lane15;
    aOff[f] = ra * 64 + ((q ^ ((ra >> 1) & 3)) << 4);
  }
  int wpb[4];
#pragma unroll
  for (int f = 0; f < 4; ++f) wpb[f] = wh * 64 + f * 16 + lane15;

  auto stageA = [&](int step, int buf) {
    const char* src = (step < 72) ? (wA1 + (size_t)step * 16384)
                                  : (wA2 + (size_t)(step - 72) * 16384);
    char* dst = ldsA0 + buf * 16384 + wv * 1024;
    const char* g = src + wv * 1024 + lane * 16;
    gll16(g, dst);
    gll16(g + 8192, dst + 8192);
  };
  auto stageB = [&](const char* plane) {
    if (plane) {
      char* dst = ldsB + 256 + wv * 1024;          // rows wp 1..128
      const char* g = plane + wv * 1024 + lane * 16;
#pragma unroll
      for (int r = 0; r < 4; ++r) gll16(g + r * 8192, dst + r * 8192);
      int4 z = {0, 0, 0, 0};
      if (t < 16) *(int4*)(ldsB + t * 16) = z;                       // row 0
      else if (t < 32) *(int4*)(ldsB + 33024 + (t - 16) * 16) = z;   // row 129
    } else {
      int4 z = {0, 0, 0, 0};
#pragma unroll
      for (int r = 0; r < 4; ++r) *(int4*)(ldsB + r * 8192 + t * 16) = z;
      if (t < 32) *(int4*)(ldsB + 32768 + t * 16) = z;
    }
  };

  int cur = 0, i = 0;
  for (int outer = 0; outer < 6; ++outer) {
    const int half = (outer >= 3) ? 1 : 0;
    const int d = outer - half * 3;
    const int hs = h + d - 1;
    const char* plane = (hs >= 0 && hs < 128)
                            ? inB1 + (size_t)hs * 65536 + (size_t)half * 32768
                            : nullptr;
    stageB(plane);
    if (outer == 0) stageA(0, 0);
    __syncthreads();
#pragma unroll
    for (int dwi = 0; dwi < 3; ++dwi) {
#pragma unroll
      for (int kc = 0; kc < 4; ++kc) {
        if (i + 1 < nsteps) stageA(i + 1, cur ^ 1);
        bf16x8 af[4], bf[4];
        const char* lA = ldsA0 + cur * 16384;
#pragma unroll
        for (int f = 0; f < 4; ++f) af[f] = *(const bf16x8*)(lA + aOff[f]);
#pragma unroll
        for (int f = 0; f < 4; ++f) {
          int wp = wpb[f] + dwi;
          bf[f] = *(const bf16x8*)(ldsB + wp * 256 + ((kc * 64 + q * 16) ^ ((wp & 7) << 4)));
        }
#pragma unroll
        for (int fm = 0; fm < 4; ++fm)
#pragma unroll
          for (int fn = 0; fn < 4; ++fn)
            acc[fm][fn] = __builtin_amdgcn_mfma_f32_16x16x32_bf16(af[fm], bf[fn], acc[fm][fn], 0, 0, 0);
        __syncthreads();
        cur ^= 1;
        ++i;
      }
    }
  }
  if (nsteps > 72) {   // fused 1x1 (c1) segment: rows h, dw=0
    for (int half2 = 0; half2 < 2; ++half2) {
      stageB(inB2 + (size_t)h * 65536 + (size_t)half2 * 32768);
      __syncthreads();
#pragma unroll
      for (int kc = 0; kc < 4; ++kc) {
        if (i + 1 < nsteps) stageA(i + 1, cur ^ 1);
        bf16x8 af[4], bf[4];
        const char* lA = ldsA0 + cur * 16384;
#pragma unroll
        for (int f = 0; f < 4; ++f) af[f] = *(const bf16x8*)(lA + aOff[f]);
#pragma unroll
        for (int f = 0; f < 4; ++f) {
          int wp = wpb[f] + 1;
          bf[f] = *(const bf16x8*)(ldsB + wp * 256 + ((kc * 64 + q * 16) ^ ((wp & 7) << 4)));
        }
#pragma unroll
        for (int fm = 0; fm < 4; ++fm)
#pragma unroll
          for (int fn = 0; fn < 4; ++fn)
            acc[fm][fn] = __builtin_amdgcn_mfma_f32_16x16x32_bf16(af[fm], bf[fn], acc[fm][fn], 0, 0, 0);
        __syncthreads();
        cur ^= 1;
        ++i;
      }
    }
  }
}

__device__ __forceinline__ void zero_acc(f32x4 (&acc)[4][4]) {
  f32x4 z = {0.f, 0.f, 0.f, 0.f};
#pragma unroll
  for (int i = 0; i < 4; ++i)
#pragma unroll
    for (int j = 0; j < 4; ++j) acc[i][j] = z;
}

// BN+ReLU, store to staging layout (8B = 4 co per lane)
__device__ __forceinline__ void store_pad_relu(f32x4 (&acc)[4][4], const float* __restrict__ st,
                                               int b, int h, char* __restrict__ out) {
  const int t = threadIdx.x, lane = t & 63, wv = t >> 6;
  const int lane15 = lane & 15, q = lane >> 4, coq = wv >> 1, wh = wv & 1;
  char* plane = out + (size_t)(b * 128 + h) * 65536;
#pragma unroll
  for (int fm = 0; fm < 4; ++fm) {
    int co = coq * 64 + fm * 16 + q * 4;
    float ss[4], tt[4];
#pragma unroll
    for (int r = 0; r < 4; ++r) { ss[r] = st[co + r]; tt[r] = st[256 + co + r]; }
#pragma unroll
    for (int fn = 0; fn < 4; ++fn) {
      int w = wh * 64 + fn * 16 + lane15;
      short4 o;
      o.x = (short)f2bf(fmaxf(acc[fm][fn][0] * ss[0] + tt[0], 0.f));
      o.y = (short)f2bf(fmaxf(acc[fm][fn][1] * ss[1] + tt[1], 0.f));
      o.z = (short)f2bf(fmaxf(acc[fm][fn][2] * ss[2] + tt[2], 0.f));
      o.w = (short)f2bf(fmaxf(acc[fm][fn][3] * ss[3] + tt[3], 0.f));
      *(short4*)(plane + (co >> 7) * 32768 + w * 256 + (((co & 127) * 2) ^ (((w + 1) & 7) << 4))) = o;
    }
  }
}

// ---------------- up conv: BN+ReLU then fused row-max over W ----------------
__global__ __launch_bounds__(512, 4) void conv_up_kernel(const char* __restrict__ xb,
                                                         const char* __restrict__ wp,
                                                         const float* __restrict__ st,
                                                         float* __restrict__ rmax) {
  __shared__ __align__(16) char lds[66048];
  int swz = (blockIdx.x & 7) * 64 + (blockIdx.x >> 3);
  int b = swz >> 7, h = swz & 127;
  f32x4 acc[4][4];
  zero_acc(acc);
  conv_pipeline(xb + (size_t)b * 8388608, nullptr, wp, nullptr, h, 72, lds, acc);

  const int t = threadIdx.x, lane = t & 63, wv = t >> 6;
  const int lane15 = lane & 15, q = lane >> 4, coq = wv >> 1, wh = wv & 1;
  float* rlds = (float*)lds;
  __syncthreads();
#pragma unroll
  for (int fm = 0; fm < 4; ++fm) {
    int co = coq * 64 + fm * 16 + q * 4;
#pragma unroll
    for (int r = 0; r < 4; ++r) {
      float ss = st[co + r], tt = st[256 + co + r];
      float v = 0.f;   // ReLU floor
#pragma unroll
      for (int fn = 0; fn < 4; ++fn) v = fmaxf(v, acc[fm][fn][r] * ss + tt);
      v = fmaxf(v, __shfl_xor(v, 1));
      v = fmaxf(v, __shfl_xor(v, 2));
      v = fmaxf(v, __shfl_xor(v, 4));
      v = fmaxf(v, __shfl_xor(v, 8));
      if (lane15 == 0) rlds[wh * 256 + co + r] = v;
    }
  }
  __syncthreads();
  if (t < 256) rmax[(size_t)(b * 128 + h) * 256 + t] = fmaxf(rlds[t], rlds[256 + t]);
}

// ---------------- down conv ----------------
__global__ __launch_bounds__(512, 4) void conv_down_kernel(const char* __restrict__ xb,
                                                           const char* __restrict__ wp,
                                                           const float* __restrict__ st,
                                                           char* __restrict__ out) {
  __shared__ __align__(16) char lds[66048];
  int swz = (blockIdx.x & 7) * 64 + (blockIdx.x >> 3);
  int b = swz >> 7, h = swz & 127;
  f32x4 acc[4][4];
  zero_acc(acc);
  conv_pipeline(xb + (size_t)b * 8388608, nullptr, wp, nullptr, h, 72, lds, acc);
  store_pad_relu(acc, st, b, h, out);
}

// ---------------- col max over H ----------------
__global__ __launch_bounds__(256) void colmax_kernel(const char* __restrict__ dp,
                                                     float* __restrict__ cmax) {
  int bw = blockIdx.x; int b = bw >> 7, w = bw & 127;
  int c = threadIdx.x;
  size_t base = (size_t)b * 8388608 + (size_t)(c >> 7) * 32768 + w * 256 +
                (((c & 127) * 2) ^ (((w + 1) & 7) << 4));
  float m = 0.f;
  for (int h = 0; h < 128; ++h) {
    u16 raw = *(const u16*)(dp + base + (size_t)h * 65536);
    m = fmaxf(m, __uint_as_float(((unsigned)raw) << 16));
  }
  cmax[(size_t)(b * 128 + w) * 256 + c] = m;
}

// ---------------- pooled = rmax[b,h,c] + cmax[b,w,c], into staging layout ----------------
__global__ __launch_bounds__(256) void pooled_kernel(const float* __restrict__ rmax,
                                                     const float* __restrict__ cmax,
                                                     char* __restrict__ dp) {
  int bh = blockIdx.x; int b = bh >> 7, h = bh & 127;
  int c = threadIdx.x;
  float rm = rmax[(size_t)(b * 128 + h) * 256 + c];
  char* plane = dp + (size_t)(b * 128 + h) * 65536 + (c >> 7) * 32768;
  int cb = (c & 127) * 2;
  for (int w = 0; w < 128; ++w) {
    float v = rm + cmax[(size_t)(b * 128 + w) * 256 + c];
    *(u16*)(plane + w * 256 + (cb ^ (((w + 1) & 7) << 4))) = f2bf(v);
  }
}

// ---------------- merge conv (pooled 3x3) + fused c1 (1x1 on xb) ----------------
__global__ __launch_bounds__(512, 4) void conv_merge_kernel(const char* __restrict__ dp,
                                                            const char* __restrict__ xb,
                                                            const char* __restrict__ wp_p,
                                                            const char* __restrict__ wp_c1,
                                                            const float* __restrict__ st,
                                                            char* __restrict__ out) {
  __shared__ __align__(16) char lds[66048];
  int swz = (blockIdx.x & 7) * 64 + (blockIdx.x >> 3);
  int b = swz >> 7, h = swz & 127;
  f32x4 acc[4][4];
  zero_acc(acc);
  conv_pipeline(dp + (size_t)b * 8388608, xb + (size_t)b * 8388608, wp_p, wp_c1, h, 80, lds, acc);
  store_pad_relu(acc, st, b, h, out);
}

// ---------------- final conv c2: BN+ReLU, NCHW fp32 out via LDS transpose ----------------
__global__ __launch_bounds__(512, 4) void conv_c2_kernel(const char* __restrict__ relu1,
                                                         const char* __restrict__ wp,
                                                         const float* __restrict__ st,
                                                         float* __restrict__ out) {
  __shared__ __align__(16) char lds[66048];
  int swz = (blockIdx.x & 7) * 64 + (blockIdx.x >> 3);
  int b = swz >> 7, h = swz & 127;
  f32x4 acc[4][4];
  zero_acc(acc);
  conv_pipeline(relu1 + (size_t)b * 8388608, nullptr, wp, nullptr, h, 72, lds, acc);

  const int t = threadIdx.x, lane = t & 63, wv = t >> 6;
  const int lane15 = lane & 15, q = lane >> 4, coq = wv >> 1, wh = wv & 1;
  float* tl = (float*)lds;   // [16][132]
  for (int g = 0; g < 16; ++g) {
    __syncthreads();
    if (coq == (g >> 2)) {
      int fm = g & 3;
      int co = coq * 64 + fm * 16 + q * 4;
#pragma unroll
      for (int r = 0; r < 4; ++r) {
        float ss = st[co + r], tt = st[256 + co + r];
#pragma unroll
        for (int fn = 0; fn < 4; ++fn) {
          int w = wh * 64 + fn * 16 + lane15;
          tl[(q * 4 + r) * 132 + w] = fmaxf(acc[fm][fn][r] * ss + tt, 0.f);
        }
      }
    }
    __syncthreads();
    int row = t >> 5, wq = (t & 31) * 4;
    float4 vv = *(float4*)&tl[row * 132 + wq];
    *(float4*)(out + (size_t)((b * 256 + g * 16 + row) * 128 + h) * 128 + wq) = vv;
  }
}

extern "C" void kernel_launch(void* const* d_in, const int* in_sizes, int n_in,
                              void* d_out, int out_size, void* d_ws, size_t ws_size,
                              hipStream_t stream) {
  (void)in_sizes; (void)n_in; (void)out_size; (void)ws_size;
  const float* x    = (const float*)d_in[0];
  const float* w_up = (const float*)d_in[1];
  const float* w_dn = (const float*)d_in[6];
  const float* w_p  = (const float*)d_in[11];
  const float* w_c1 = (const float*)d_in[16];
  const float* w_c2 = (const float*)d_in[21];

  // ws layout (bytes) — total 106,571,776
  char* ws = (char*)d_ws;
  char* xb    = ws;                         // 33,554,432 (32MB staging layout)
  char* dp    = ws + 33554432ull;           // 33,554,432 (down, then pooled)
  char* relu1 = ws + 67108864ull;           // 33,554,432
  u16* wp_up  = (u16*)(ws + 100663296ull);  // 1,179,648
  u16* wp_dn  = (u16*)(ws + 101842944ull);  // 1,179,648
  u16* wp_p   = (u16*)(ws + 103022592ull);  // 1,179,648
  u16* wp_c2  = (u16*)(ws + 104202240ull);  // 1,179,648
  u16* wp_c1  = (u16*)(ws + 105381888ull);  // 131,072
  float* st   = (float*)(ws + 105512960ull);// 10,240
  float* rmax = (float*)(ws + 105523200ull);// 524,288
  float* cmax = (float*)(ws + 106047488ull);// 524,288

  bn_prep_kernel<<<1, 256, 0, stream>>>((const float*)d_in[2], (const float*)d_in[3],
                                        (const float*)d_in[4], (const float*)d_in[5], st);
  bn_prep_kernel<<<1, 256, 0, stream>>>((const float*)d_in[7], (const float*)d_in[8],
                                        (const float*)d_in[9], (const float*)d_in[10], st + 512);
  bn_prep_kernel<<<1, 256, 0, stream>>>((const float*)d_in[12], (const float*)d_in[13],
                                        (const float*)d_in[14], (const float*)d_in[15], st + 1024);
  bn_prep_kernel<<<1, 256, 0, stream>>>((const float*)d_in[17], (const float*)d_in[18],
                                        (const float*)d_in[19], (const float*)d_in[20], st + 1536);
  bn_prep_kernel<<<1, 256, 0, stream>>>((const float*)d_in[22], (const float*)d_in[23],
                                        (const float*)d_in[24], (const float*)d_in[25], st + 2048);
  bn_fix_kernel<<<1, 256, 0, stream>>>(st);

  wprep3_kernel<<<2304, 256, 0, stream>>>(w_up, wp_up);
  wprep3_kernel<<<2304, 256, 0, stream>>>(w_dn, wp_dn);
  wprep3_kernel<<<2304, 256, 0, stream>>>(w_p, wp_p);
  wprep3_kernel<<<2304, 256, 0, stream>>>(w_c2, wp_c2);
  wprep1_kernel<<<256, 256, 0, stream>>>(w_c1, wp_c1, st + 1536);

  nchw_to_nhwc_kernel<<<512, 256, 0, stream>>>(x, xb);

  conv_up_kernel<<<512, 512, 0, stream>>>(xb, (const char*)wp_up, st, rmax);
  conv_down_kernel<<<512, 512, 0, stream>>>(xb, (const char*)wp_dn, st + 512, dp);
  colmax_kernel<<<512, 256, 0, stream>>>(dp, cmax);
  pooled_kernel<<<512, 256, 0, stream>>>(rmax, cmax, dp);
  conv_merge_kernel<<<512, 512, 0, stream>>>(dp, xb, (const char*)wp_p, (const char*)wp_c1,
                                             st + 1024, relu1);
  conv_c2_kernel<<<512, 512, 0, stream>>>(relu1, (const char*)wp_c2, st + 2048, (float*)d_out);
}